// Round 1
// baseline (4780.180 us; speedup 1.0000x reference)
//
#include <hip/hip_runtime.h>
#include <hip/hip_bf16.h>

// Problem constants
#define B_    16
#define C_    96
#define H_    224
#define W_    224
#define COUT_ 96
#define GH_   14
#define GW_   14
#define P_    196          // GH_*GW_
#define HW_   (H_*W_)      // 50176

typedef __attribute__((ext_vector_type(8))) unsigned short ushort8;

__device__ __forceinline__ unsigned short f2bf(float f) {
    __hip_bfloat16 h = __float2bfloat16(f);
    union { __hip_bfloat16 h; unsigned short u; } cv; cv.h = h; return cv.u;
}
__device__ __forceinline__ float bf2f(unsigned short u) {
    return __uint_as_float(((unsigned)u) << 16);
}

// ---------------------------------------------------------------------------
// Kernel 1: per-patch depthwise 3x3 conv (patch-local zero padding).
// x:  (B, C, H, W) f32, NCHW
// pf: (C, P, 1, 3, 3) f32
// sa: (B, H, W, C) bf16  (NHWC -- layout chosen for the future MFMA conv2)
// One block per (b, patch). Thread = one pixel of the 16x16 patch.
// ---------------------------------------------------------------------------
__global__ __launch_bounds__(256) void sa_kernel(const float* __restrict__ x,
                                                 const float* __restrict__ pf,
                                                 unsigned short* __restrict__ sa) {
    int bid   = blockIdx.x;          // b*P_ + patch
    int patch = bid % P_;
    int b     = bid / P_;
    int gh = patch / GW_, gw = patch % GW_;
    int t  = threadIdx.x;
    int py = t >> 4, px = t & 15;
    int y  = gh * 16 + py, xx = gw * 16 + px;

    const float* xb = x + (size_t)b * C_ * HW_;
    unsigned short* sap = sa + (((size_t)b * H_ + y) * W_ + xx) * C_;

    for (int c0 = 0; c0 < C_; c0 += 8) {
        ushort8 v;
        #pragma unroll
        for (int j = 0; j < 8; ++j) {
            int c = c0 + j;
            const float* xc = xb + (size_t)c * HW_;
            const float* w  = pf + ((size_t)c * P_ + patch) * 9;   // block-uniform -> s_load
            float acc = 0.f;
            #pragma unroll
            for (int dy = -1; dy <= 1; ++dy) {
                int yy = py + dy;
                #pragma unroll
                for (int dx = -1; dx <= 1; ++dx) {
                    int xp = px + dx;
                    // patch-local zero padding: clip to [0,16)
                    if (yy >= 0 && yy < 16 && xp >= 0 && xp < 16) {
                        acc = fmaf(xc[(size_t)(gh * 16 + yy) * W_ + (gw * 16 + xp)],
                                   w[(dy + 1) * 3 + (dx + 1)], acc);
                    }
                }
            }
            v[j] = f2bf(acc);
        }
        *reinterpret_cast<ushort8*>(sap + c0) = v;   // 16B store, c-contiguous
    }
}

// ---------------------------------------------------------------------------
// Kernel 2: dense 3x3 conv (full-image padding) + exact GELU.
// sa:  (B, H, W, C) bf16
// of:  (COUT, C, 3, 3) f32
// out: (B, COUT, H, W) f32
// Block = one 16x16 spatial tile (patch-aligned) x 16 couts.
// Thread = one pixel, acc[16] couts. Loop c in chunks of 8 staged in LDS.
// ---------------------------------------------------------------------------
__global__ __launch_bounds__(256) void conv2_kernel(const unsigned short* __restrict__ sa,
                                                    const float* __restrict__ of,
                                                    float* __restrict__ out) {
    int bid = blockIdx.x;
    int cg  = bid % 6;  int tmp = bid / 6;
    int patch = tmp % P_; int b = tmp / P_;
    int gh = patch / GW_, gw = patch % GW_;
    int y0 = gh * 16, x0 = gw * 16;
    int cout0 = cg * 16;
    int t  = threadIdx.x;
    int py = t >> 4, px = t & 15;

    __shared__ ushort8 lds[324];    // 18x18 halo tile x 8 channels (5.2 KB)

    float acc[16];
    #pragma unroll
    for (int i = 0; i < 16; ++i) acc[i] = 0.f;

    for (int c0 = 0; c0 < C_; c0 += 8) {
        __syncthreads();            // protect LDS from previous chunk's readers
        for (int v = t; v < 324; v += 256) {
            int r = v / 18, cc = v % 18;
            int gy = y0 - 1 + r, gx = x0 - 1 + cc;
            ushort8 val = {0, 0, 0, 0, 0, 0, 0, 0};
            if (gy >= 0 && gy < H_ && gx >= 0 && gx < W_)
                val = *reinterpret_cast<const ushort8*>(
                        sa + (((size_t)b * H_ + gy) * W_ + gx) * C_ + c0);
            lds[v] = val;
        }
        __syncthreads();

        // Unpack this thread's 3x3 window of 8 channels.
        float s[3][3][8];
        #pragma unroll
        for (int dy = 0; dy < 3; ++dy)
            #pragma unroll
            for (int dx = 0; dx < 3; ++dx) {
                ushort8 v = lds[(py + dy) * 18 + (px + dx)];
                #pragma unroll
                for (int j = 0; j < 8; ++j) s[dy][dx][j] = bf2f(v[j]);
            }

        const float* ofp = of + ((size_t)cout0 * C_ + c0) * 9;  // block-uniform
        #pragma unroll
        for (int j = 0; j < 8; ++j)
            #pragma unroll
            for (int k = 0; k < 9; ++k) {
                float sv = s[k / 3][k % 3][j];
                #pragma unroll
                for (int i = 0; i < 16; ++i)
                    acc[i] = fmaf(sv, ofp[(size_t)i * C_ * 9 + j * 9 + k], acc[i]);
            }
    }

    // Exact GELU + store (coalesced per cout).
    int y = y0 + py, xx = x0 + px;
    float* op = out + ((size_t)b * COUT_ + cout0) * HW_ + (size_t)y * W_ + xx;
    #pragma unroll
    for (int i = 0; i < 16; ++i) {
        float v = acc[i];
        op[(size_t)i * HW_] = 0.5f * v * (1.0f + erff(v * 0.70710678118f));
    }
}

extern "C" void kernel_launch(void* const* d_in, const int* in_sizes, int n_in,
                              void* d_out, int out_size, void* d_ws, size_t ws_size,
                              hipStream_t stream) {
    const float* x  = (const float*)d_in[0];
    const float* pf = (const float*)d_in[1];
    const float* of = (const float*)d_in[2];
    float* out = (float*)d_out;
    unsigned short* sa = (unsigned short*)d_ws;   // needs 154,140,672 bytes

    sa_kernel<<<B_ * P_, 256, 0, stream>>>(x, pf, sa);
    conv2_kernel<<<B_ * P_ * 6, 256, 0, stream>>>(sa, of, out);
}

// Round 2
// 736.155 us; speedup vs baseline: 6.4934x; 6.4934x over previous
//
#include <hip/hip_runtime.h>
#include <hip/hip_bf16.h>

#define B_    16
#define C_    96
#define H_    224
#define W_    224
#define COUT_ 96
#define GH_   14
#define GW_   14
#define P_    196          // GH_*GW_
#define HW_   (H_*W_)      // 50176

typedef __attribute__((ext_vector_type(8))) unsigned short ushort8;
typedef __attribute__((ext_vector_type(8))) short        short8;   // MFMA bf16x8 operand
typedef __attribute__((ext_vector_type(4))) float        f32x4;

__device__ __forceinline__ unsigned short f2bf(float f) {
    union { __hip_bfloat16 h; unsigned short u; } cv;
    cv.h = __float2bfloat16(f);
    return cv.u;
}

// ---------------------------------------------------------------------------
// Kernel 0: transform output_filters (COUT, C, 3, 3) f32 -> ofb[tap][cout][c] bf16
// so B-fragments (8 consecutive channels, fixed cout) are one ushort8 load.
// ---------------------------------------------------------------------------
__global__ __launch_bounds__(256) void prep_ofb(const float* __restrict__ of,
                                                unsigned short* __restrict__ ofb) {
    int idx = blockIdx.x * 256 + threadIdx.x;      // 9*96*96 = 82944
    if (idx < 9 * 96 * 96) {
        int tap = idx / (96 * 96);
        int r   = idx % (96 * 96);
        int cout = r / 96, c = r % 96;
        ofb[idx] = f2bf(of[((size_t)cout * 96 + c) * 9 + tap]);
    }
}

// ---------------------------------------------------------------------------
// Kernel 1: per-patch depthwise 3x3 conv (patch-local zero padding).
// x: (B,C,H,W) f32 -> sa: (B,H,W,C) bf16, fully-coalesced output stores.
// Block = (b, patch), 256 threads (thread = pixel).
// ---------------------------------------------------------------------------
__global__ __launch_bounds__(256) void sa_kernel(const float* __restrict__ x,
                                                 const float* __restrict__ pf,
                                                 unsigned short* __restrict__ sa) {
    int bid   = blockIdx.x;
    int patch = bid % P_;
    int b     = bid / P_;
    int gh = patch / GW_, gw = patch % GW_;
    int t  = threadIdx.x;
    int py = t >> 4, px = t & 15;

    __shared__ float   xs[8][256];     // 8 KB: one 8-channel slice of the patch
    __shared__ ushort8 os8[3072];      // 48 KB: 256 px x 96 ch bf16 (pixel-major)
    unsigned short* os = (unsigned short*)os8;

    const size_t xbase = ((size_t)b * C_) * HW_ + (size_t)(gh * 16 + py) * W_ + (gw * 16 + px);

    for (int c0 = 0; c0 < C_; c0 += 8) {
        __syncthreads();               // xs reuse guard
        #pragma unroll
        for (int j = 0; j < 8; ++j)
            xs[j][t] = x[xbase + (size_t)(c0 + j) * HW_];
        __syncthreads();

        ushort8 v;
        #pragma unroll
        for (int j = 0; j < 8; ++j) {
            const float* wgt = pf + ((size_t)(c0 + j) * P_ + patch) * 9;  // block-uniform
            float acc = 0.f;
            #pragma unroll
            for (int dy = -1; dy <= 1; ++dy) {
                int yy = py + dy;
                #pragma unroll
                for (int dx = -1; dx <= 1; ++dx) {
                    int xp = px + dx;
                    if (yy >= 0 && yy < 16 && xp >= 0 && xp < 16)
                        acc = fmaf(xs[j][yy * 16 + xp], wgt[(dy + 1) * 3 + (dx + 1)], acc);
                }
            }
            v[j] = f2bf(acc);
        }
        *(ushort8*)&os[t * 96 + c0] = v;
    }
    __syncthreads();

    // Coalesced store: 16 rows x (16 px * 96 ch) contiguous bf16.
    for (int k = 0; k < 12; ++k) {
        int chunk = k * 256 + t;           // 3072 ushort8 chunks
        int prow  = chunk / 192;
        int off   = chunk % 192;
        *(ushort8*)&sa[(((size_t)b * H_ + gh * 16 + prow) * W_ + gw * 16) * 96 + off * 8] =
            os8[chunk];
    }
}

// ---------------------------------------------------------------------------
// Kernel 2: dense 3x3 conv as implicit GEMM (M=256 px tile, N=96, K=864) + GELU.
// sa: (B,H,W,C) bf16; ofb: [tap][cout][c] bf16; out: (B,COUT,H,W) f32.
// 4 waves; wave w owns pixel rows 64w..64w+63. 18x18x96 halo tile in LDS.
// ---------------------------------------------------------------------------
__global__ __launch_bounds__(256) void conv2_mfma(const unsigned short* __restrict__ sa,
                                                  const unsigned short* __restrict__ ofb,
                                                  float* __restrict__ out) {
    // XCD-aware swizzle (3136 % 8 == 0 -> bijective)
    int bid0 = blockIdx.x;
    int bid  = (bid0 % 8) * (3136 / 8) + bid0 / 8;
    int patch = bid % P_;
    int b     = bid / P_;
    int gh = patch / GW_, gw = patch % GW_;
    int y0 = gh * 16 - 1, x0 = gw * 16 - 1;   // halo origin

    int t = threadIdx.x;
    int w = t >> 6, l = t & 63;
    int mrow = l & 15, kgrp = l >> 4;

    __shared__ ushort8 atile8[3888];          // 18*18 px * 96 ch bf16 = 62208 B
    unsigned short* at = (unsigned short*)atile8;

    // ---- stage halo tile (zero-padded at image edges) ----
    for (int v = t; v < 3888; v += 256) {
        int r  = v / 216;                 // halo row 0..17
        int q  = v % 216;
        int xp = q / 12;                  // halo col 0..17
        int ch = (q % 12) * 8;
        int gy = y0 + r, gx = x0 + xp;
        ushort8 val = {0, 0, 0, 0, 0, 0, 0, 0};
        if (gy >= 0 && gy < H_ && gx >= 0 && gx < W_)
            val = *(const ushort8*)&sa[(((size_t)b * H_ + gy) * W_ + gx) * 96 + ch];
        atile8[v] = val;
    }
    __syncthreads();

    f32x4 acc[4][6];
    #pragma unroll
    for (int mi = 0; mi < 4; ++mi)
        #pragma unroll
        for (int ni = 0; ni < 6; ++ni)
            acc[mi][ni] = (f32x4)0.f;

    // ---- K loop: 9 taps x 3 chunks of 32 channels ----
    #pragma unroll 1
    for (int tap = 0; tap < 9; ++tap) {
        int ky = tap / 3, kx = tap % 3;
        const unsigned short* bofs = ofb + tap * 96 * 96;
        #pragma unroll
        for (int cs = 0; cs < 3; ++cs) {
            int c0 = cs * 32 + kgrp * 8;
            short8 bf[6];
            #pragma unroll
            for (int ni = 0; ni < 6; ++ni)
                bf[ni] = *(const short8*)&bofs[(ni * 16 + mrow) * 96 + c0];
            #pragma unroll
            for (int mi = 0; mi < 4; ++mi) {
                int hrow = w * 4 + mi + ky;
                int hcol = mrow + kx;
                short8 af = *(const short8*)&at[(hrow * 18 + hcol) * 96 + c0];
                #pragma unroll
                for (int ni = 0; ni < 6; ++ni)
                    acc[mi][ni] = __builtin_amdgcn_mfma_f32_16x16x32_bf16(
                        af, bf[ni], acc[mi][ni], 0, 0, 0);
            }
        }
    }

    // ---- epilogue: exact GELU + dwordx4 stores (4 consecutive px per frag) ----
    #pragma unroll
    for (int mi = 0; mi < 4; ++mi) {
        int py = w * 4 + mi;              // patch-local row
        int gy = gh * 16 + py;
        #pragma unroll
        for (int ni = 0; ni < 6; ++ni) {
            int cout = ni * 16 + mrow;
            f32x4 g;
            #pragma unroll
            for (int j = 0; j < 4; ++j) {
                float v = acc[mi][ni][j];
                g[j] = 0.5f * v * (1.0f + erff(v * 0.70710678118f));
            }
            *(f32x4*)&out[((size_t)b * COUT_ + cout) * HW_ + (size_t)gy * W_ +
                          gw * 16 + kgrp * 4] = g;
        }
    }
}

extern "C" void kernel_launch(void* const* d_in, const int* in_sizes, int n_in,
                              void* d_out, int out_size, void* d_ws, size_t ws_size,
                              hipStream_t stream) {
    const float* x  = (const float*)d_in[0];
    const float* pf = (const float*)d_in[1];
    const float* of = (const float*)d_in[2];
    float* out = (float*)d_out;

    unsigned short* sa  = (unsigned short*)d_ws;                       // 154,140,672 B
    unsigned short* ofb = (unsigned short*)((char*)d_ws + 154140672);  // + 165,888 B

    prep_ofb<<<324, 256, 0, stream>>>(of, ofb);
    sa_kernel<<<B_ * P_, 256, 0, stream>>>(x, pf, sa);
    conv2_mfma<<<B_ * P_, 256, 0, stream>>>(sa, ofb, out);
}